// Round 4
// baseline (51.565 us; speedup 1.0000x reference)
//
#include <hip/hip_runtime.h>

// MTGP covariance via bf16 hi/lo-split MFMA, round 4: 32x32 wave-tiles.
// cov[i,j] = sum_z W[ti,z]W[tj,z]*th[z,0]*exp(-0.5*th[z,1]*||Xi-Xj||^2) + 0.002*I
// M=4096, D=64, Z=4, fp32 in/out.
// prep: X -> Xhi,Xlo (bf16 rne split) + row norms, in d_ws.
// main: 8256 upper-tri 32x32 wave-tiles, 4 waves/block (2064 blocks),
// 16x16x32 bf16 MFMA (hh+hl+lh), fused RBF epilogue, direct + transposed
// stores (exact once coverage). No LDS, no barriers.

#define M_PTS 4096
#define DIM 64
#define JITTER_F 0.002f
#define NEG_HALF_LOG2E (-0.72134752044448170f)  // -0.5*log2(e)
#define NSLAB 128                                // 4096/32
#define NITEM 8256                               // 128*129/2
#define NBLK (NITEM / 4)                         // 2064

typedef __attribute__((ext_vector_type(8))) short short8v;   // 8 bf16
typedef __attribute__((ext_vector_type(4))) float f32x4;

union FragU { short8v v; uint2 h[2]; };

__device__ __forceinline__ float fast_exp2(float x) {
#if defined(__has_builtin)
#if __has_builtin(__builtin_amdgcn_exp2f)
  return __builtin_amdgcn_exp2f(x);
#else
  return exp2f(x);
#endif
#else
  return exp2f(x);
#endif
}

__device__ __forceinline__ unsigned bfr(float x) {  // fp32 -> bf16 (rne), as u16
  unsigned u = __float_as_uint(x);
  return (u + 0x7FFFu + ((u >> 16) & 1u)) >> 16;
}
__device__ __forceinline__ float bff(unsigned h) {  // bf16 bits -> fp32
  return __uint_as_float(h << 16);
}

// ---------------- prep: hi/lo split + row norms ----------------
__global__ __launch_bounds__(64) void mtgp_prep(
    const float* __restrict__ X, unsigned short* __restrict__ Xhi,
    unsigned short* __restrict__ Xlo, float* __restrict__ sqn) {
  const int row = blockIdx.x * 64 + threadIdx.x;  // 0..4095
  const float4* xr = (const float4*)(X + (size_t)row * DIM);
  unsigned* hp = (unsigned*)(Xhi + (size_t)row * DIM);
  unsigned* lp = (unsigned*)(Xlo + (size_t)row * DIM);
  float s = 0.0f;
#define CVT2(xa, xb, oidx) { \
    unsigned ha = bfr(xa), hb = bfr(xb); \
    hp[oidx] = ha | (hb << 16); \
    unsigned la = bfr((xa) - bff(ha)), lb = bfr((xb) - bff(hb)); \
    lp[oidx] = la | (lb << 16); \
    s = fmaf((xa), (xa), s); s = fmaf((xb), (xb), s); }
#pragma unroll
  for (int i = 0; i < 16; ++i) {
    float4 vv = xr[i];
    CVT2(vv.x, vv.y, 2 * i)
    CVT2(vv.z, vv.w, 2 * i + 1)
  }
#undef CVT2
  sqn[row] = s;
}

// ---------------- main: one wave = one 32x32 upper-tri tile ----------------
__global__ __launch_bounds__(256, 4) void mtgp_main(
    const unsigned short* __restrict__ Xhi, const unsigned short* __restrict__ Xlo,
    const float* __restrict__ sqn, const float* __restrict__ W,
    const float* __restrict__ theta, float* __restrict__ out) {
  const int wid = threadIdx.x >> 6;
  const int lane = threadIdx.x & 63;
  const int item = blockIdx.x * 4 + wid;          // 0..8255

  // decode item -> (u, v), v >= u, 128 slabs; prefix(u) = u*(257-u)/2
  int u = (int)((257.0f - sqrtf((float)(66049 - 8 * item))) * 0.5f);
  if (u < 0) u = 0;
  if (u > 127) u = 127;
  while (u > 0 && u * (257 - u) / 2 > item) --u;
  while (u < 127 && (u + 1) * (256 - u) / 2 <= item) ++u;
  const int v = u + (item - u * (257 - u) / 2);
  const int gi0 = u << 5, gj0 = v << 5;

  const int r16 = lane & 15;   // row (A) / col (B) within 16-slab
  const int kg = lane >> 4;    // k-group
  const int kg4 = kg << 2;

  f32x4 acc[2][2];
#pragma unroll
  for (int p = 0; p < 2; ++p)
#pragma unroll
    for (int q = 0; q < 2; ++q) acc[p][q] = (f32x4)0.0f;

#pragma unroll
  for (int k0 = 0; k0 < 2; ++k0) {
    const int oe = k0 * 32 + kg4;  // ushort offset of low k-half for this lane
    FragU ah[2], al[2], bh[2], bl[2];
#pragma unroll
    for (int p = 0; p < 2; ++p) {
      const unsigned short* rah = Xhi + (size_t)(gi0 + p * 16 + r16) * DIM;
      const unsigned short* ral = Xlo + (size_t)(gi0 + p * 16 + r16) * DIM;
      const unsigned short* rbh = Xhi + (size_t)(gj0 + p * 16 + r16) * DIM;
      const unsigned short* rbl = Xlo + (size_t)(gj0 + p * 16 + r16) * DIM;
      ah[p].h[0] = *(const uint2*)&rah[oe];
      ah[p].h[1] = *(const uint2*)&rah[oe + 16];
      al[p].h[0] = *(const uint2*)&ral[oe];
      al[p].h[1] = *(const uint2*)&ral[oe + 16];
      bh[p].h[0] = *(const uint2*)&rbh[oe];
      bh[p].h[1] = *(const uint2*)&rbh[oe + 16];
      bl[p].h[0] = *(const uint2*)&rbl[oe];
      bl[p].h[1] = *(const uint2*)&rbl[oe + 16];
    }
#pragma unroll
    for (int p = 0; p < 2; ++p)
#pragma unroll
      for (int q = 0; q < 2; ++q) {
        acc[p][q] = __builtin_amdgcn_mfma_f32_16x16x32_bf16(ah[p].v, bh[q].v, acc[p][q], 0, 0, 0);
        acc[p][q] = __builtin_amdgcn_mfma_f32_16x16x32_bf16(ah[p].v, bl[q].v, acc[p][q], 0, 0, 0);
        acc[p][q] = __builtin_amdgcn_mfma_f32_16x16x32_bf16(al[p].v, bh[q].v, acc[p][q], 0, 0, 0);
      }
  }

  // ---- epilogue: sd = max(sq_i + sq_j - 2*dot, 0); v = sum_z cz*exp2(ez*sd) ----
  const int ti = u >> 5, tj = v >> 5;  // 32 slabs of 32 rows per task
  float czv[4], ezv[4];
#pragma unroll
  for (int z = 0; z < 4; ++z) {
    czv[z] = W[ti * 4 + z] * W[tj * 4 + z] * theta[2 * z];
    ezv[z] = NEG_HALF_LOG2E * theta[2 * z + 1];
  }
  f32x4 sqr[2];
  float sqc[2];
#pragma unroll
  for (int p = 0; p < 2; ++p) sqr[p] = *(const f32x4*)&sqn[gi0 + p * 16 + kg4];
#pragma unroll
  for (int q = 0; q < 2; ++q) sqc[q] = sqn[gj0 + q * 16 + r16];

#pragma unroll
  for (int p = 0; p < 2; ++p)
#pragma unroll
    for (int q = 0; q < 2; ++q)
#pragma unroll
      for (int r = 0; r < 4; ++r) {
        const float d = acc[p][q][r];
        const float sd = fmaxf(fmaf(-2.0f, d, sqr[p][r] + sqc[q]), 0.0f);
        float val = czv[0] * fast_exp2(ezv[0] * sd);
        val = fmaf(czv[1], fast_exp2(ezv[1] * sd), val);
        val = fmaf(czv[2], fast_exp2(ezv[2] * sd), val);
        val = fmaf(czv[3], fast_exp2(ezv[3] * sd), val);
        acc[p][q][r] = val;
      }

  if (u == v) {  // jitter on global diagonal (C/D: row = kg4+r, col = r16)
#pragma unroll
    for (int p = 0; p < 2; ++p)
#pragma unroll
      for (int r = 0; r < 4; ++r)
        if (kg4 + r == r16) acc[p][p][r] += JITTER_F;
  }

  // ---- direct store (rows gi0.., cols gj0..) ----
#pragma unroll
  for (int p = 0; p < 2; ++p)
#pragma unroll
    for (int r = 0; r < 4; ++r) {
      float* rp = out + (size_t)(gi0 + p * 16 + kg4 + r) * M_PTS + gj0 + r16;
      rp[0] = acc[p][0][r];
      rp[16] = acc[p][1][r];
    }
  // ---- transposed store (off-diagonal only; disjoint, coalesced float4) ----
  if (u != v) {
#pragma unroll
    for (int q = 0; q < 2; ++q)
#pragma unroll
      for (int p = 0; p < 2; ++p) {
        f32x4* tp = (f32x4*)(out + (size_t)(gj0 + q * 16 + r16) * M_PTS + gi0 + p * 16 + kg4);
        *tp = acc[p][q];
      }
  }
}

extern "C" void kernel_launch(void* const* d_in, const int* in_sizes, int n_in,
                              void* d_out, int out_size, void* d_ws, size_t ws_size,
                              hipStream_t stream) {
  const float* x     = (const float*)d_in[0];   // (4,1024,64)
  const float* W     = (const float*)d_in[1];   // (4,4)
  const float* theta = (const float*)d_in[2];   // (4,2)
  float* out = (float*)d_out;                   // (4096,4096)

  // workspace layout: sq (16 KB) | Xhi (512 KB) | Xlo (512 KB)
  float* sqn = (float*)d_ws;
  unsigned short* Xhi = (unsigned short*)((char*)d_ws + 16384);
  unsigned short* Xlo = (unsigned short*)((char*)d_ws + 16384 + 524288);

  mtgp_prep<<<dim3(M_PTS / 64), dim3(64), 0, stream>>>(x, Xhi, Xlo, sqn);
  mtgp_main<<<dim3(NBLK), dim3(256), 0, stream>>>(Xhi, Xlo, sqn, W, theta, out);
}

// Round 5
// 31.519 us; speedup vs baseline: 1.6360x; 1.6360x over previous
//
#include <hip/hip_runtime.h>

// MTGP covariance, round 5: LDS-staged bf16 hi/lo MFMA, 64x128 block tiles.
// cov[i,j] = sum_z W[ti,z]W[tj,z]*th[z,0]*exp(-0.5*th[z,1]*||Xi-Xj||^2) + 0.002*I
// prep: X -> Xhi,Xlo (bf16 rne split) + row norms, in d_ws.
// main: 1056 tiles (64 rows x 128 cols, tiles not fully below diagonal).
// Coalesced dwordx4 staging -> 48KB swizzled LDS -> ds_read_b64 fragments ->
// 16x16x32 bf16 MFMA (hh+hl+lh) -> fused RBF epilogue.
// Exact-once coverage: direct-store half h iff 2c+h >= r;
// transpose-store half h iff 2c+h >= r+1. Deterministic, no double writes.

#define M_PTS 4096
#define DIM 64
#define JITTER_F 0.002f
#define NEG_HALF_LOG2E (-0.72134752044448170f)  // -0.5*log2(e)
#define NBLK 1056

typedef __attribute__((ext_vector_type(8))) short short8v;   // 8 bf16
typedef __attribute__((ext_vector_type(4))) float f32x4;

union FragU { short8v v; uint2 h[2]; };

__device__ __forceinline__ float fast_exp2(float x) {
#if defined(__has_builtin)
#if __has_builtin(__builtin_amdgcn_exp2f)
  return __builtin_amdgcn_exp2f(x);
#else
  return exp2f(x);
#endif
#else
  return exp2f(x);
#endif
}

__device__ __forceinline__ unsigned bfr(float x) {  // fp32 -> bf16 (rne), as u16
  unsigned u = __float_as_uint(x);
  return (u + 0x7FFFu + ((u >> 16) & 1u)) >> 16;
}
__device__ __forceinline__ float bff(unsigned h) {  // bf16 bits -> fp32
  return __uint_as_float(h << 16);
}

// ---------------- prep: hi/lo split + row norms ----------------
__global__ __launch_bounds__(256) void mtgp_prep(
    const float* __restrict__ X, unsigned short* __restrict__ Xhi,
    unsigned short* __restrict__ Xlo, float* __restrict__ sqn) {
  const int row = blockIdx.x * 256 + threadIdx.x;  // 0..4095
  const float4* xr = (const float4*)(X + (size_t)row * DIM);
  unsigned* hp = (unsigned*)(Xhi + (size_t)row * DIM);
  unsigned* lp = (unsigned*)(Xlo + (size_t)row * DIM);
  float s = 0.0f;
#define CVT2(xa, xb, oidx) { \
    unsigned ha = bfr(xa), hb = bfr(xb); \
    hp[oidx] = ha | (hb << 16); \
    unsigned la = bfr((xa) - bff(ha)), lb = bfr((xb) - bff(hb)); \
    lp[oidx] = la | (lb << 16); \
    s = fmaf((xa), (xa), s); s = fmaf((xb), (xb), s); }
#pragma unroll
  for (int i = 0; i < 16; ++i) {
    float4 vv = xr[i];
    CVT2(vv.x, vv.y, 2 * i)
    CVT2(vv.z, vv.w, 2 * i + 1)
  }
#undef CVT2
  sqn[row] = s;
}

// ---------------- main ----------------
__global__ __launch_bounds__(256, 3) void mtgp_main(
    const unsigned short* __restrict__ Xhi, const unsigned short* __restrict__ Xlo,
    const float* __restrict__ sqn, const float* __restrict__ W,
    const float* __restrict__ theta, float* __restrict__ out) {
  // LDS panels, XOR-swizzled: element-ush e of row r stored at
  // r*64 + (((e>>3) ^ (r&7))<<3) + (e&7)
  __shared__ unsigned short Ahi[64 * 64], Alo[64 * 64];    // 8KB + 8KB
  __shared__ unsigned short Bhi[128 * 64], Blo[128 * 64];  // 16KB + 16KB

  // ---- decode blockIdx -> (r, c): row-slab r (64 rows), col-slab c (128 cols),
  //      kept iff c >= r>>1 (tile not fully below diagonal) ----
  int rem = blockIdx.x, r = 0;
  while (rem >= 32 - (r >> 1)) { rem -= 32 - (r >> 1); ++r; }
  const int c = (r >> 1) + rem;
  const int grow0 = r << 6;   // first global row
  const int gcol0 = c << 7;   // first global col

  const int tid = threadIdx.x;

  // ---- stage panels (coalesced dwordx4, swizzled LDS writes) ----
#pragma unroll
  for (int cc = 0; cc < 2; ++cc) {
    const int n = cc * 256 + tid;          // 0..511
    const int row = n >> 3, sl = n & 7;
    const int gofs = (grow0 + row) * DIM + sl * 8;
    const int lofs = row * 64 + (((sl ^ (row & 7))) << 3);
    *(uint4*)&Ahi[lofs] = *(const uint4*)&Xhi[gofs];
    *(uint4*)&Alo[lofs] = *(const uint4*)&Xlo[gofs];
  }
#pragma unroll
  for (int cc = 0; cc < 4; ++cc) {
    const int n = cc * 256 + tid;          // 0..1023
    const int row = n >> 3, sl = n & 7;
    const int gofs = (gcol0 + row) * DIM + sl * 8;
    const int lofs = row * 64 + (((sl ^ (row & 7))) << 3);
    *(uint4*)&Bhi[lofs] = *(const uint4*)&Xhi[gofs];
    *(uint4*)&Blo[lofs] = *(const uint4*)&Xlo[gofs];
  }
  __syncthreads();

  const int wid = tid >> 6, lane = tid & 63;
  const int half = wid >> 1;               // 64-col half of the tile
  const int j6 = 2 * c + half;
  const bool doD = (j6 >= r);              // direct-store this half
  const bool doT = (j6 >= r + 1);          // transpose-store this half
  if (!doD && !doT) return;                // fully-below half: no work (after barrier)

  const int r16 = lane & 15, kg = lane >> 4, kg4 = kg << 2;
  const int wcol = wid << 5;               // wave col offset in tile (0/32/64/96)

  f32x4 acc[4][2];
#pragma unroll
  for (int p = 0; p < 4; ++p) { acc[p][0] = (f32x4)0.0f; acc[p][1] = (f32x4)0.0f; }

  // fragment LDS read: row rr, k-half k0, lane kg/r16.
  // elements [k0*32+kg*4 .. +3] and [+16 .. +19]
#define FRAG_LD(dst, PANEL, rr) { \
    const int rb = (rr) * 64, sw = (rr) & 7; \
    dst.h[0] = *(const uint2*)&PANEL[rb + (((sl1) ^ sw) << 3) + hof]; \
    dst.h[1] = *(const uint2*)&PANEL[rb + (((sl1 + 2) ^ sw) << 3) + hof]; }

#pragma unroll
  for (int k0 = 0; k0 < 2; ++k0) {
    const int sl1 = k0 * 4 + (kg >> 1);
    const int hof = (kg & 1) * 4;
    FragU ah[4], al[4], bh[2], bl[2];
#pragma unroll
    for (int p = 0; p < 4; ++p) {
      const int rowp = p * 16 + r16;
      FRAG_LD(ah[p], Ahi, rowp)
      FRAG_LD(al[p], Alo, rowp)
    }
#pragma unroll
    for (int q = 0; q < 2; ++q) {
      const int rowq = wcol + q * 16 + r16;
      FRAG_LD(bh[q], Bhi, rowq)
      FRAG_LD(bl[q], Blo, rowq)
    }
#pragma unroll
    for (int p = 0; p < 4; ++p)
#pragma unroll
      for (int q = 0; q < 2; ++q) {
        acc[p][q] = __builtin_amdgcn_mfma_f32_16x16x32_bf16(ah[p].v, bh[q].v, acc[p][q], 0, 0, 0);
        acc[p][q] = __builtin_amdgcn_mfma_f32_16x16x32_bf16(ah[p].v, bl[q].v, acc[p][q], 0, 0, 0);
        acc[p][q] = __builtin_amdgcn_mfma_f32_16x16x32_bf16(al[p].v, bh[q].v, acc[p][q], 0, 0, 0);
      }
  }
#undef FRAG_LD

  // ---- epilogue ----
  const int ti = r >> 4, tj = c >> 3;      // task ids (1024 rows/task)
  float czv[4], ezv[4];
#pragma unroll
  for (int z = 0; z < 4; ++z) {
    czv[z] = W[ti * 4 + z] * W[tj * 4 + z] * theta[2 * z];
    ezv[z] = NEG_HALF_LOG2E * theta[2 * z + 1];
  }
  f32x4 sqr[4];
#pragma unroll
  for (int p = 0; p < 4; ++p) sqr[p] = *(const f32x4*)&sqn[grow0 + p * 16 + kg4];
  float sqc[2];
#pragma unroll
  for (int q = 0; q < 2; ++q) sqc[q] = sqn[gcol0 + wcol + q * 16 + r16];

  const int gcol_lane = gcol0 + wcol + r16;  // + q*16
#pragma unroll
  for (int p = 0; p < 4; ++p)
#pragma unroll
    for (int q = 0; q < 2; ++q)
#pragma unroll
      for (int rr = 0; rr < 4; ++rr) {
        const float d = acc[p][q][rr];
        const float sd = fmaxf(fmaf(-2.0f, d, sqr[p][rr] + sqc[q]), 0.0f);
        float val = czv[0] * fast_exp2(ezv[0] * sd);
        val = fmaf(czv[1], fast_exp2(ezv[1] * sd), val);
        val = fmaf(czv[2], fast_exp2(ezv[2] * sd), val);
        val = fmaf(czv[3], fast_exp2(ezv[3] * sd), val);
        if (grow0 + p * 16 + kg4 + rr == gcol_lane + q * 16) val += JITTER_F;
        acc[p][q][rr] = val;
      }

  // ---- direct store: full half (rows grow0.., cols gcol0+wcol..) ----
  if (doD) {
#pragma unroll
    for (int p = 0; p < 4; ++p)
#pragma unroll
      for (int rr = 0; rr < 4; ++rr) {
        float* rp = out + (size_t)(grow0 + p * 16 + kg4 + rr) * M_PTS + gcol_lane;
        rp[0] = acc[p][0][rr];
        rp[16] = acc[p][1][rr];
      }
  }
  // ---- transpose store: half entirely above diagonal -> below-diag mirror ----
  if (doT) {
#pragma unroll
    for (int q = 0; q < 2; ++q)
#pragma unroll
      for (int p = 0; p < 4; ++p) {
        f32x4* tp = (f32x4*)(out + (size_t)(gcol_lane + q * 16) * M_PTS + grow0 + p * 16 + kg4);
        *tp = acc[p][q];
      }
  }
}

extern "C" void kernel_launch(void* const* d_in, const int* in_sizes, int n_in,
                              void* d_out, int out_size, void* d_ws, size_t ws_size,
                              hipStream_t stream) {
  const float* x     = (const float*)d_in[0];   // (4,1024,64)
  const float* W     = (const float*)d_in[1];   // (4,4)
  const float* theta = (const float*)d_in[2];   // (4,2)
  float* out = (float*)d_out;                   // (4096,4096)

  // workspace: sq (16 KB) | Xhi (512 KB) | Xlo (512 KB)
  float* sqn = (float*)d_ws;
  unsigned short* Xhi = (unsigned short*)((char*)d_ws + 16384);
  unsigned short* Xlo = (unsigned short*)((char*)d_ws + 16384 + 524288);

  mtgp_prep<<<dim3(M_PTS / 256), dim3(256), 0, stream>>>(x, Xhi, Xlo, sqn);
  mtgp_main<<<dim3(NBLK), dim3(256), 0, stream>>>(Xhi, Xlo, sqn, W, theta, out);
}

// Round 6
// 26.760 us; speedup vs baseline: 1.9270x; 1.1779x over previous
//
#include <hip/hip_runtime.h>

// MTGP covariance, round 6: 64x64 tiles, 32KB LDS, 5 blocks/CU residency.
// cov[i,j] = sum_z W[ti,z]W[tj,z]*th[z,0]*exp(-0.5*th[z,1]*||Xi-Xj||^2) + 0.002*I
// prep: X -> Xhi,Xlo (bf16 rne split) + row norms (4 thr/row), in d_ws.
// main: 2080 upper-tri 64x64 tiles, 4 waves in 2x2 grid (wave = 32x32),
// coalesced staging -> swizzled LDS -> ds_read_b64 frags -> 16x16x32 bf16
// MFMA (hh+hl+lh) -> fused RBF epilogue -> direct + (off-diag) transpose
// stores. Exact-once line coverage at 64-slab granularity: J>=I direct,
// J<I transpose. Deterministic.

#define M_PTS 4096
#define DIM 64
#define JITTER_F 0.002f
#define NEG_HALF_LOG2E (-0.72134752044448170f)  // -0.5*log2(e)
#define NBLK 2080                                // 64*65/2

typedef __attribute__((ext_vector_type(8))) short short8v;   // 8 bf16
typedef __attribute__((ext_vector_type(4))) float f32x4;

union FragU { short8v v; uint2 h[2]; };

__device__ __forceinline__ float fast_exp2(float x) {
#if defined(__has_builtin)
#if __has_builtin(__builtin_amdgcn_exp2f)
  return __builtin_amdgcn_exp2f(x);
#else
  return exp2f(x);
#endif
#else
  return exp2f(x);
#endif
}

__device__ __forceinline__ unsigned bfr(float x) {  // fp32 -> bf16 (rne), as u16
  unsigned u = __float_as_uint(x);
  return (u + 0x7FFFu + ((u >> 16) & 1u)) >> 16;
}
__device__ __forceinline__ float bff(unsigned h) {  // bf16 bits -> fp32
  return __uint_as_float(h << 16);
}

// ---------------- prep: hi/lo split + row norms (4 threads per row) ----------------
__global__ __launch_bounds__(256) void mtgp_prep(
    const float* __restrict__ X, unsigned short* __restrict__ Xhi,
    unsigned short* __restrict__ Xlo, float* __restrict__ sqn) {
  const int gtid = blockIdx.x * 256 + threadIdx.x;  // 0..16383
  const int row = gtid >> 2, part = gtid & 3;       // 16 elems per thread
  const float4* xr = (const float4*)(X + (size_t)row * DIM + part * 16);
  unsigned* hp = (unsigned*)(Xhi + (size_t)row * DIM + part * 16);
  unsigned* lp = (unsigned*)(Xlo + (size_t)row * DIM + part * 16);
  float s = 0.0f;
#define CVT2(xa, xb, oidx) { \
    unsigned ha = bfr(xa), hb = bfr(xb); \
    hp[oidx] = ha | (hb << 16); \
    unsigned la = bfr((xa) - bff(ha)), lb = bfr((xb) - bff(hb)); \
    lp[oidx] = la | (lb << 16); \
    s = fmaf((xa), (xa), s); s = fmaf((xb), (xb), s); }
#pragma unroll
  for (int i = 0; i < 4; ++i) {
    float4 vv = xr[i];
    CVT2(vv.x, vv.y, 2 * i)
    CVT2(vv.z, vv.w, 2 * i + 1)
  }
#undef CVT2
  s += __shfl_xor(s, 1);
  s += __shfl_xor(s, 2);
  if (part == 0) sqn[row] = s;
}

// ---------------- main: 64x64 upper-tri tiles, 2x2 waves of 32x32 ----------------
__global__ __launch_bounds__(256, 5) void mtgp_main(
    const unsigned short* __restrict__ Xhi, const unsigned short* __restrict__ Xlo,
    const float* __restrict__ sqn, const float* __restrict__ W,
    const float* __restrict__ theta, float* __restrict__ out) {
  // LDS panels, XOR-swizzled: ush element e of row r at r*64 + (((e>>3)^(r&7))<<3) + (e&7)
  __shared__ unsigned short Ahi[64 * 64], Alo[64 * 64];  // 8KB each
  __shared__ unsigned short Bhi[64 * 64], Blo[64 * 64];  // 8KB each  (32KB total)

  // ---- decode item -> (u, v), v >= u, 64 slabs; prefix(u) = u*(129-u)/2 ----
  const int item = blockIdx.x;
  int u = (int)(64.5f - sqrtf(4160.25f - 2.0f * (float)item));
  if (u < 0) u = 0;
  if (u > 63) u = 63;
  while (u > 0 && u * (129 - u) / 2 > item) --u;
  while (u < 63 && (u + 1) * (128 - u) / 2 <= item) ++u;
  const int v = u + (item - u * (129 - u) / 2);
  const int grow0 = u << 6, gj0 = v << 6;

  const int tid = threadIdx.x;

  // ---- stage panels (coalesced uint4, swizzled LDS writes): 2 uint4/panel/thread ----
#pragma unroll
  for (int cc = 0; cc < 2; ++cc) {
    const int n = cc * 256 + tid;          // 0..511
    const int row = n >> 3, sl = n & 7;
    const int lofs = row * 64 + ((sl ^ (row & 7)) << 3);
    const int ga = (grow0 + row) * DIM + sl * 8;
    const int gb = (gj0 + row) * DIM + sl * 8;
    *(uint4*)&Ahi[lofs] = *(const uint4*)&Xhi[ga];
    *(uint4*)&Alo[lofs] = *(const uint4*)&Xlo[ga];
    *(uint4*)&Bhi[lofs] = *(const uint4*)&Xhi[gb];
    *(uint4*)&Blo[lofs] = *(const uint4*)&Xlo[gb];
  }
  __syncthreads();

  const int wid = tid >> 6, lane = tid & 63;
  const int wr = (wid >> 1) << 5;          // wave row offset (0/32)
  const int wc = (wid & 1) << 5;           // wave col offset (0/32)
  const int r16 = lane & 15, kg = lane >> 4, kg4 = kg << 2;

  f32x4 acc[2][2];
#pragma unroll
  for (int p = 0; p < 2; ++p) { acc[p][0] = (f32x4)0.0f; acc[p][1] = (f32x4)0.0f; }

  // fragment read: row rr, k-slice via (sl1, hof): elements [k0*32+kg*4..+3], [+16..+19]
#define FRAG_LD(dst, PANEL, rr) { \
    const int rb = (rr) * 64, sw = (rr) & 7; \
    dst.h[0] = *(const uint2*)&PANEL[rb + ((sl1 ^ sw) << 3) + hof]; \
    dst.h[1] = *(const uint2*)&PANEL[rb + (((sl1 + 2) ^ sw) << 3) + hof]; }

#pragma unroll
  for (int k0 = 0; k0 < 2; ++k0) {
    const int sl1 = k0 * 4 + (kg >> 1);
    const int hof = (kg & 1) * 4;
    FragU ah[2], al[2], bh[2], bl[2];
#pragma unroll
    for (int p = 0; p < 2; ++p) {
      const int ra = wr + p * 16 + r16;
      const int rb2 = wc + p * 16 + r16;
      FRAG_LD(ah[p], Ahi, ra)
      FRAG_LD(al[p], Alo, ra)
      FRAG_LD(bh[p], Bhi, rb2)
      FRAG_LD(bl[p], Blo, rb2)
    }
#pragma unroll
    for (int p = 0; p < 2; ++p)
#pragma unroll
      for (int q = 0; q < 2; ++q) {
        acc[p][q] = __builtin_amdgcn_mfma_f32_16x16x32_bf16(ah[p].v, bh[q].v, acc[p][q], 0, 0, 0);
        acc[p][q] = __builtin_amdgcn_mfma_f32_16x16x32_bf16(ah[p].v, bl[q].v, acc[p][q], 0, 0, 0);
        acc[p][q] = __builtin_amdgcn_mfma_f32_16x16x32_bf16(al[p].v, bh[q].v, acc[p][q], 0, 0, 0);
      }
  }
#undef FRAG_LD

  // ---- epilogue ----
  const int ti = u >> 4, tj = v >> 4;      // 16 slabs of 64 rows per task
  float czv[4], ezv[4];
#pragma unroll
  for (int z = 0; z < 4; ++z) {
    czv[z] = W[ti * 4 + z] * W[tj * 4 + z] * theta[2 * z];
    ezv[z] = NEG_HALF_LOG2E * theta[2 * z + 1];
  }
  f32x4 sqr[2];
#pragma unroll
  for (int p = 0; p < 2; ++p) sqr[p] = *(const f32x4*)&sqn[grow0 + wr + p * 16 + kg4];
  float sqc[2];
#pragma unroll
  for (int q = 0; q < 2; ++q) sqc[q] = sqn[gj0 + wc + q * 16 + r16];

#pragma unroll
  for (int p = 0; p < 2; ++p)
#pragma unroll
    for (int q = 0; q < 2; ++q)
#pragma unroll
      for (int rr = 0; rr < 4; ++rr) {
        const float d = acc[p][q][rr];
        const float sd = fmaxf(fmaf(-2.0f, d, sqr[p][rr] + sqc[q]), 0.0f);
        float val = czv[0] * fast_exp2(ezv[0] * sd);
        val = fmaf(czv[1], fast_exp2(ezv[1] * sd), val);
        val = fmaf(czv[2], fast_exp2(ezv[2] * sd), val);
        val = fmaf(czv[3], fast_exp2(ezv[3] * sd), val);
        if (u == v && wr + p * 16 + kg4 + rr == wc + q * 16 + r16) val += JITTER_F;
        acc[p][q][rr] = val;
      }

  // ---- direct store: rows grow0+wr.., cols gj0+wc.. (both 64B halves per wave) ----
#pragma unroll
  for (int p = 0; p < 2; ++p)
#pragma unroll
    for (int rr = 0; rr < 4; ++rr) {
      float* rp = out + (size_t)(grow0 + wr + p * 16 + kg4 + rr) * M_PTS + gj0 + wc + r16;
      rp[0] = acc[p][0][rr];
      rp[16] = acc[p][1][rr];
    }
  // ---- transpose store (off-diagonal only): mirror to strictly-below region ----
  if (u != v) {
#pragma unroll
    for (int q = 0; q < 2; ++q)
#pragma unroll
      for (int p = 0; p < 2; ++p) {
        f32x4* tp = (f32x4*)(out + (size_t)(gj0 + wc + q * 16 + r16) * M_PTS + grow0 + wr + p * 16 + kg4);
        *tp = acc[p][q];
      }
  }
}

extern "C" void kernel_launch(void* const* d_in, const int* in_sizes, int n_in,
                              void* d_out, int out_size, void* d_ws, size_t ws_size,
                              hipStream_t stream) {
  const float* x     = (const float*)d_in[0];   // (4,1024,64)
  const float* W     = (const float*)d_in[1];   // (4,4)
  const float* theta = (const float*)d_in[2];   // (4,2)
  float* out = (float*)d_out;                   // (4096,4096)

  // workspace: sq (16 KB) | Xhi (512 KB) | Xlo (512 KB)
  float* sqn = (float*)d_ws;
  unsigned short* Xhi = (unsigned short*)((char*)d_ws + 16384);
  unsigned short* Xlo = (unsigned short*)((char*)d_ws + 16384 + 524288);

  mtgp_prep<<<dim3(64), dim3(256), 0, stream>>>(x, Xhi, Xlo, sqn);
  mtgp_main<<<dim3(NBLK), dim3(256), 0, stream>>>(Xhi, Xlo, sqn, W, theta, out);
}

// Round 7
// 24.290 us; speedup vs baseline: 2.1229x; 1.1017x over previous
//
#include <hip/hip_runtime.h>

// MTGP covariance, round 7: single fused kernel.
// cov[i,j] = sum_z W[ti,z]W[tj,z]*th[z,0]*exp(-0.5*th[z,1]*||Xi-Xj||^2) + 0.002*I
// M=4096, D=64, Z=4, fp32 in/out.
// 2080 upper-tri 64x64 tiles, 4 waves (2x2 grid of 32x32). Per block:
//  - stage fp32 X rows -> in-register bf16 hi/lo split -> k-permuted,
//    XOR-swizzled LDS panels (32 KB exactly -> 5 blocks/CU)
//  - row norms via paired-lane shuffle, kept in a VGPR through the K-loop,
//    published into dead panel LDS after a post-K barrier
//  - K-loop: 16 ds_read_b128 frags + 24 mfma_f32_16x16x32_bf16 (hh+hl+lh)
//  - fused RBF epilogue; direct + (off-diag) transpose stores, exact-once.
// k-permutation (slot f = k0*4+kg holds elems {32k0+4kg+j, 32k0+16+4kg+j})
// is applied identically to A and B operands => dot products unchanged.

#define M_PTS 4096
#define DIM 64
#define JITTER_F 0.002f
#define NEG_HALF_LOG2E (-0.72134752044448170f)  // -0.5*log2(e)
#define NBLK 2080                                // 64*65/2

typedef __attribute__((ext_vector_type(8))) short short8v;   // 8 bf16
typedef __attribute__((ext_vector_type(4))) float f32x4;

union FragU { short8v v; uint4 u; };

__device__ __forceinline__ float fast_exp2(float x) {
#if defined(__has_builtin)
#if __has_builtin(__builtin_amdgcn_exp2f)
  return __builtin_amdgcn_exp2f(x);
#else
  return exp2f(x);
#endif
#else
  return exp2f(x);
#endif
}

__device__ __forceinline__ unsigned bfr(float x) {  // fp32 -> bf16 (rne), as u16
  unsigned u = __float_as_uint(x);
  return (u + 0x7FFFu + ((u >> 16) & 1u)) >> 16;
}
__device__ __forceinline__ float bff(unsigned h) {  // bf16 bits -> fp32
  return __uint_as_float(h << 16);
}

__global__ __launch_bounds__(256, 5) void mtgp_fused(
    const float* __restrict__ X,      // [4096,64]
    const float* __restrict__ W,      // [4,4]
    const float* __restrict__ theta,  // [4,2]
    float* __restrict__ out) {        // [4096,4096]
  // Panels: row r, 16B slot f stored at ush offset r*64 + ((f ^ (r&7))<<3).
  __shared__ unsigned short Ahi[64 * 64], Alo[64 * 64];  // 8KB each
  __shared__ unsigned short Bhi[64 * 64], Blo[64 * 64];  // 8KB each (32KB total)

  // ---- decode item -> (u, v), v >= u, 64 slabs; prefix(u) = u*(129-u)/2 ----
  const int item = blockIdx.x;
  int u = (int)(64.5f - sqrtf(4160.25f - 2.0f * (float)item));
  if (u < 0) u = 0;
  if (u > 63) u = 63;
  while (u > 0 && u * (129 - u) / 2 > item) --u;
  while (u < 63 && (u + 1) * (128 - u) / 2 <= item) ++u;
  const int v = u + (item - u * (129 - u) / 2);
  const int grow0 = u << 6, gj0 = v << 6;

  const int tid = threadIdx.x;

  // ---- fused staging: fp32 -> hi/lo split -> k-permuted swizzled LDS ----
  // thread t: panel = (t<128 ? A : B), row = (t&127)>>1, half = t&1 (32 floats)
  const int half = tid & 1;
  const int srow = (tid & 127) >> 1;
  const bool isB = (tid >= 128);
  const int gsrow = (isB ? gj0 : grow0) + srow;
  const float4* xr = (const float4*)(X + (size_t)gsrow * DIM + half * 32);
  unsigned short* Ph = isB ? Bhi : Ahi;
  unsigned short* Pl = isB ? Blo : Alo;
  float s = 0.0f;  // row-half norm partial (fixed order -> deterministic)
#pragma unroll
  for (int kgs = 0; kgs < 4; ++kgs) {
    const float4 v0 = xr[kgs];        // locals 4k..4k+3
    const float4 v1 = xr[kgs + 4];    // locals 16+4k..16+4k+3
    s = fmaf(v0.x, v0.x, s); s = fmaf(v0.y, v0.y, s);
    s = fmaf(v0.z, v0.z, s); s = fmaf(v0.w, v0.w, s);
    s = fmaf(v1.x, v1.x, s); s = fmaf(v1.y, v1.y, s);
    s = fmaf(v1.z, v1.z, s); s = fmaf(v1.w, v1.w, s);
    const unsigned h0 = bfr(v0.x), h1 = bfr(v0.y), h2 = bfr(v0.z), h3 = bfr(v0.w);
    const unsigned h4 = bfr(v1.x), h5 = bfr(v1.y), h6 = bfr(v1.z), h7 = bfr(v1.w);
    uint4 hv = make_uint4(h0 | (h1 << 16), h2 | (h3 << 16),
                          h4 | (h5 << 16), h6 | (h7 << 16));
    const unsigned l0 = bfr(v0.x - bff(h0)), l1 = bfr(v0.y - bff(h1));
    const unsigned l2 = bfr(v0.z - bff(h2)), l3 = bfr(v0.w - bff(h3));
    const unsigned l4 = bfr(v1.x - bff(h4)), l5 = bfr(v1.y - bff(h5));
    const unsigned l6 = bfr(v1.z - bff(h6)), l7 = bfr(v1.w - bff(h7));
    uint4 lv = make_uint4(l0 | (l1 << 16), l2 | (l3 << 16),
                          l4 | (l5 << 16), l6 | (l7 << 16));
    const int f = (half << 2) + kgs;
    const int lofs = srow * 64 + ((f ^ (srow & 7)) << 3);
    *(uint4*)&Ph[lofs] = hv;
    *(uint4*)&Pl[lofs] = lv;
  }
  s += __shfl_xor(s, 1);  // pair (t, t^1) = two halves of the same row
  __syncthreads();

  const int wid = tid >> 6, lane = tid & 63;
  const int wr = (wid >> 1) << 5;          // wave row offset (0/32)
  const int wc = (wid & 1) << 5;           // wave col offset (0/32)
  const int r16 = lane & 15, kg = lane >> 4, kg4 = kg << 2;

  f32x4 acc[2][2];
#pragma unroll
  for (int p = 0; p < 2; ++p) { acc[p][0] = (f32x4)0.0f; acc[p][1] = (f32x4)0.0f; }

  // frag: lane (kg,r16) reads 16B slot f0 = k0*4+kg of row rr (one b128)
#define FRAG_LD(dst, PANEL, rr) { \
    dst.u = *(const uint4*)&PANEL[(rr) * 64 + ((f0 ^ ((rr) & 7)) << 3)]; }

#pragma unroll
  for (int k0 = 0; k0 < 2; ++k0) {
    const int f0 = (k0 << 2) + kg;
    FragU ah[2], al[2], bh[2], bl[2];
#pragma unroll
    for (int p = 0; p < 2; ++p) {
      const int ra = wr + p * 16 + r16;
      const int rb = wc + p * 16 + r16;
      FRAG_LD(ah[p], Ahi, ra)
      FRAG_LD(al[p], Alo, ra)
      FRAG_LD(bh[p], Bhi, rb)
      FRAG_LD(bl[p], Blo, rb)
    }
#pragma unroll
    for (int p = 0; p < 2; ++p)
#pragma unroll
      for (int q = 0; q < 2; ++q) {
        acc[p][q] = __builtin_amdgcn_mfma_f32_16x16x32_bf16(ah[p].v, bh[q].v, acc[p][q], 0, 0, 0);
        acc[p][q] = __builtin_amdgcn_mfma_f32_16x16x32_bf16(ah[p].v, bl[q].v, acc[p][q], 0, 0, 0);
        acc[p][q] = __builtin_amdgcn_mfma_f32_16x16x32_bf16(al[p].v, bh[q].v, acc[p][q], 0, 0, 0);
      }
  }
#undef FRAG_LD

  // ---- publish row norms into dead panel LDS ----
  __syncthreads();                         // all frag reads complete
  if (half == 0) ((float*)Ahi)[(isB ? 64 : 0) + srow] = s;
  __syncthreads();
  const float* nrm = (const float*)Ahi;    // [0..63]=A rows, [64..127]=B rows

  // ---- epilogue ----
  const int ti = u >> 4, tj = v >> 4;      // 16 slabs of 64 rows per task
  float czv[4], ezv[4];
#pragma unroll
  for (int z = 0; z < 4; ++z) {
    czv[z] = W[ti * 4 + z] * W[tj * 4 + z] * theta[2 * z];
    ezv[z] = NEG_HALF_LOG2E * theta[2 * z + 1];
  }
  f32x4 sqr[2];
#pragma unroll
  for (int p = 0; p < 2; ++p) sqr[p] = *(const f32x4*)&nrm[wr + p * 16 + kg4];
  float sqc[2];
#pragma unroll
  for (int q = 0; q < 2; ++q) sqc[q] = nrm[64 + wc + q * 16 + r16];

#pragma unroll
  for (int p = 0; p < 2; ++p)
#pragma unroll
    for (int q = 0; q < 2; ++q)
#pragma unroll
      for (int rr = 0; rr < 4; ++rr) {
        const float d = acc[p][q][rr];
        const float sd = fmaxf(fmaf(-2.0f, d, sqr[p][rr] + sqc[q]), 0.0f);
        float val = czv[0] * fast_exp2(ezv[0] * sd);
        val = fmaf(czv[1], fast_exp2(ezv[1] * sd), val);
        val = fmaf(czv[2], fast_exp2(ezv[2] * sd), val);
        val = fmaf(czv[3], fast_exp2(ezv[3] * sd), val);
        if (u == v && wr + p * 16 + kg4 + rr == wc + q * 16 + r16) val += JITTER_F;
        acc[p][q][rr] = val;
      }

  // ---- direct store: rows grow0+wr.., cols gj0+wc.. ----
#pragma unroll
  for (int p = 0; p < 2; ++p)
#pragma unroll
    for (int rr = 0; rr < 4; ++rr) {
      float* rp = out + (size_t)(grow0 + wr + p * 16 + kg4 + rr) * M_PTS + gj0 + wc + r16;
      rp[0] = acc[p][0][rr];
      rp[16] = acc[p][1][rr];
    }
  // ---- transpose store (off-diagonal only): mirror to strictly-below region ----
  if (u != v) {
#pragma unroll
    for (int q = 0; q < 2; ++q)
#pragma unroll
      for (int p = 0; p < 2; ++p) {
        f32x4* tp = (f32x4*)(out + (size_t)(gj0 + wc + q * 16 + r16) * M_PTS + grow0 + wr + p * 16 + kg4);
        *tp = acc[p][q];
      }
  }
}

extern "C" void kernel_launch(void* const* d_in, const int* in_sizes, int n_in,
                              void* d_out, int out_size, void* d_ws, size_t ws_size,
                              hipStream_t stream) {
  const float* x     = (const float*)d_in[0];   // (4,1024,64)
  const float* W     = (const float*)d_in[1];   // (4,4)
  const float* theta = (const float*)d_in[2];   // (4,2)
  float* out = (float*)d_out;                   // (4096,4096)

  mtgp_fused<<<dim3(NBLK), dim3(256), 0, stream>>>(x, W, theta, out);
}